// Round 21
// baseline (162.951 us; speedup 1.0000x reference)
//
#include <hip/hip_runtime.h>
#include <stdint.h>

#define N_NODES 100000
#define N_EDGES 1200000
#define HID 64
#define NGRAPH 512
#define NCLS 2
#define BN_EPS 1e-5f

#define NTILES (N_NODES / 16)     // 6250, exact
#define NBLK_G2 782               // ceil(6250/8) — gemm2 grid (2 tiles/wave, 4 waves)

// bucket sort: 256-node buckets, fixed-capacity staging (uint32: code|src|dstl)
#define BKT_SH 8
#define BKT_NODES 256
#define NB 391                     // ceil(100000/256)
#define BKT_CAP 4080               // mean 3069 + 18 sigma; 391*4080*4B = 6.38MB
#define EB_PER_BLK 4096            // edges per k_bucket block (256 thr x 16)
#define NBLK_E 293                 // ceil(1200000/4096)

typedef __attribute__((ext_vector_type(8))) short short8;   // 8 bf16 = 4 VGPRs
typedef __attribute__((ext_vector_type(4))) float f32x4;

__device__ inline float bf2f(uint32_t hi16) {
    uint32_t u = hi16 << 16;
    return __builtin_bit_cast(float, u);
}
__device__ inline uint32_t f2bf_rtn(float f) {             // round-to-nearest-even
    uint32_t u = __builtin_bit_cast(uint32_t, f);
    return (u + 0x7FFFu + ((u >> 16) & 1u)) >> 16;
}

// ---------------- node code + zero accumulators (replaces memsets) ----------------
__global__ void k_code(const int* __restrict__ sid, const int* __restrict__ cid,
                       unsigned char* __restrict__ code8,
                       int* __restrict__ bucket_cnt, float* __restrict__ stats) {
    int i = blockIdx.x * blockDim.x + threadIdx.x;
    if (i < N_NODES) code8[i] = (unsigned char)(sid[i] | (cid[i] << 4));
    if (blockIdx.x == 0) {
        for (int j = threadIdx.x; j < NB; j += 256) bucket_cnt[j] = 0;
        for (int j = threadIdx.x; j < 4 * HID; j += 256) stats[j] = 0.f;
    }
}

// ---------------- layer-1 tables ----------------
__global__ __launch_bounds__(256) void k_tab(const float* __restrict__ sW,
                                             const float* __restrict__ cW,
                                             const float* __restrict__ W1l,
                                             const float* __restrict__ W1r,
                                             const float* __restrict__ b1,
                                             float* __restrict__ TsL,
                                             ushort* __restrict__ tblR) {
    int gid = blockIdx.x * 256 + threadIdx.x;
    if (gid < 24 * 64) {
        int row = gid >> 6, d = gid & 63;
        const float* e = (row < 16) ? &sW[row * 64] : &cW[(row - 16) * 64];
        float acc = 0.f;
        #pragma unroll 8
        for (int k = 0; k < 64; ++k) acc += e[k] * W1l[k * 64 + d];
        TsL[gid] = acc;
    } else if (gid < 24 * 64 + 128 * 64) {
        int r = gid - 24 * 64;
        int c = r >> 6, d = r & 63;
        int s = c & 15, cl = c >> 4;
        float acc = b1[d];
        #pragma unroll 8
        for (int k = 0; k < 64; ++k)
            acc += (sW[s * 64 + k] + cW[cl * 64 + k]) * W1r[k * 64 + d];
        tblR[r] = (ushort)f2bf_rtn(acc);
    }
}

// ---------------- bucket CSR build: pack code|src|dstl in uint32 staged --------
__global__ __launch_bounds__(256) void k_bucket(const int* __restrict__ src,
                                                const int* __restrict__ dst,
                                                const unsigned char* __restrict__ code8,
                                                int* __restrict__ bucket_cnt,
                                                uint32_t* __restrict__ staged) {
    __shared__ int h[NB];
    __shared__ int cur[NB];
    int tid = threadIdx.x;
    for (int j = tid; j < NB; j += 256) h[j] = 0;
    __syncthreads();
    uint32_t pk[16];
    int bk[16];
    int base = blockIdx.x * EB_PER_BLK;
    #pragma unroll
    for (int i = 0; i < 16; ++i) {
        int e = base + i * 256 + tid;
        if (e < N_EDGES) {
            int s = src[e], d = dst[e];
            int c = code8[s];
            bk[i] = d >> BKT_SH;
            pk[i] = ((uint32_t)c << 25) | ((uint32_t)s << 8)
                  | (uint32_t)(d & (BKT_NODES - 1));
            atomicAdd(&h[bk[i]], 1);
        } else {
            bk[i] = -1;
        }
    }
    __syncthreads();
    for (int j = tid; j < NB; j += 256)
        cur[j] = (h[j] > 0) ? atomicAdd(&bucket_cnt[j], h[j]) : 0;
    __syncthreads();
    #pragma unroll
    for (int i = 0; i < 16; ++i) {
        if (bk[i] >= 0) {
            int slot = atomicAdd(&cur[bk[i]], 1);
            staged[(size_t)bk[i] * BKT_CAP + slot] = pk[i];
        }
    }
}

// scan NB bucket counts -> bucket_off (global csr offsets)
__global__ __launch_bounds__(512) void k_bscan(const int* __restrict__ bucket_cnt,
                                               int* __restrict__ bucket_off,
                                               int* __restrict__ row_ptr) {
    __shared__ int sh[512];
    int t = threadIdx.x;
    int v = (t < NB) ? bucket_cnt[t] : 0;
    sh[t] = v;
    __syncthreads();
    #pragma unroll
    for (int off = 1; off < 512; off <<= 1) {
        int cur = sh[t];
        int u = (t >= off) ? sh[t - off] : 0;
        __syncthreads();
        sh[t] = cur + u;
        __syncthreads();
    }
    if (t < NB) bucket_off[t] = sh[t] - v;
    if (t == 0) {
        bucket_off[NB] = N_EDGES;
        row_ptr[N_NODES] = N_EDGES;
    }
}

// ---------------- place + histogram + fused layer-1 (256-node buckets) ----------
__global__ __launch_bounds__(256) void k_place(const uint32_t* __restrict__ staged,
                                               const int* __restrict__ bucket_off,
                                               const unsigned char* __restrict__ code8,
                                               const float* __restrict__ TsL,
                                               const ushort* __restrict__ tblR,
                                               int* __restrict__ row_ptr,
                                               int* __restrict__ csr_src,
                                               ushort* __restrict__ h1b,
                                               float* __restrict__ sums,
                                               float* __restrict__ sumsq) {
    __shared__ int hist[BKT_NODES];
    __shared__ int cursor[BKT_NODES];
    __shared__ int part[256];
    __shared__ int cnt24[BKT_NODES * 12];   // 12 KB
    __shared__ float lsum[4][64];
    __shared__ float lsq[4][64];
    int b = blockIdx.x;
    int tid = threadIdx.x;
    int lane = tid & 63, wv = tid >> 6;
    int cc = tid & 15;
    int nodes0 = b << BKT_SH;
    int nn = min(BKT_NODES, N_NODES - nodes0);
    int ebeg = bucket_off[b];
    int cntb = bucket_off[b + 1] - ebeg;
    const uint32_t* st = &staged[(size_t)b * BKT_CAP];

    f32x4 trow[24];
    #pragma unroll
    for (int s = 0; s < 24; ++s)
        trow[s] = *(const f32x4*)&TsL[s * 64 + cc * 4];

    hist[tid] = 0;
    #pragma unroll
    for (int j = 0; j < 12; ++j) cnt24[tid * 12 + j] = 0;
    __syncthreads();
    for (int e = tid; e < cntb; e += 256)
        atomicAdd(&hist[(int)(st[e] & (BKT_NODES - 1))], 1);
    __syncthreads();
    int myc = hist[tid];
    part[tid] = myc;
    __syncthreads();
    #pragma unroll
    for (int off = 1; off < 256; off <<= 1) {
        int curv = part[tid];
        int u = (tid >= off) ? part[tid - off] : 0;
        __syncthreads();
        part[tid] = curv + u;
        __syncthreads();
    }
    int ex = ebeg + part[tid] - myc;
    cursor[tid] = ex;
    if (tid < nn) row_ptr[nodes0 + tid] = ex;
    __syncthreads();
    for (int e = tid; e < cntb; e += 256) {
        uint32_t pk = st[e];
        int nl = (int)(pk & (BKT_NODES - 1));
        int slot = atomicAdd(&cursor[nl], 1);
        csr_src[slot] = (int)((pk >> 8) & 0x1FFFFu);
        int c = (int)(pk >> 25);
        int sb = c & 15, cb = c >> 4;
        atomicAdd(&cnt24[nl * 12 + (sb >> 1)], 1 << ((sb & 1) * 16));
        atomicAdd(&cnt24[nl * 12 + 8 + (cb >> 1)], 1 << ((cb & 1) * 16));
    }
    __syncthreads();

    float sv0 = 0, sv1 = 0, sv2 = 0, sv3 = 0;
    float qv0 = 0, qv1 = 0, qv2 = 0, qv3 = 0;
    int nrow = tid >> 4;                     // 0..15
    for (int it = 0; it < 16; ++it) {
        int nl = it * 16 + nrow;
        if (nl >= nn) continue;
        int node = nodes0 + nl;
        int cw[12];
        *(uint4*)&cw[0] = *(const uint4*)&cnt24[nl * 12];
        *(uint4*)&cw[4] = *(const uint4*)&cnt24[nl * 12 + 4];
        *(uint4*)&cw[8] = *(const uint4*)&cnt24[nl * 12 + 8];
        int deg = hist[nl];
        float a0 = 0, a1 = 0, a2 = 0, a3 = 0;
        #pragma unroll
        for (int ss = 0; ss < 24; ++ss) {
            int j = (ss < 16) ? (ss >> 1) : (8 + ((ss - 16) >> 1));
            float w = (float)((cw[j] >> ((ss & 1) * 16)) & 0xFFFF);
            a0 += w * trow[ss].x; a1 += w * trow[ss].y;
            a2 += w * trow[ss].z; a3 += w * trow[ss].w;
        }
        float inv = 1.f / (float)max(deg, 1);
        int ci = code8[node];
        uint2 trv = *(const uint2*)&tblR[ci * 64 + cc * 4];
        float h0 = fmaf(a0, inv, bf2f(trv.x & 0xFFFFu));
        float h1 = fmaf(a1, inv, bf2f(trv.x >> 16));
        float h2 = fmaf(a2, inv, bf2f(trv.y & 0xFFFFu));
        float h3 = fmaf(a3, inv, bf2f(trv.y >> 16));
        uint2 o;
        o.x = f2bf_rtn(h0) | (f2bf_rtn(h1) << 16);
        o.y = f2bf_rtn(h2) | (f2bf_rtn(h3) << 16);
        *(uint2*)&h1b[(size_t)node * HID + cc * 4] = o;
        sv0 += h0; qv0 += h0 * h0;
        sv1 += h1; qv1 += h1 * h1;
        sv2 += h2; qv2 += h2 * h2;
        sv3 += h3; qv3 += h3 * h3;
    }
    sv0 += __shfl_xor(sv0, 16); sv0 += __shfl_xor(sv0, 32);
    sv1 += __shfl_xor(sv1, 16); sv1 += __shfl_xor(sv1, 32);
    sv2 += __shfl_xor(sv2, 16); sv2 += __shfl_xor(sv2, 32);
    sv3 += __shfl_xor(sv3, 16); sv3 += __shfl_xor(sv3, 32);
    qv0 += __shfl_xor(qv0, 16); qv0 += __shfl_xor(qv0, 32);
    qv1 += __shfl_xor(qv1, 16); qv1 += __shfl_xor(qv1, 32);
    qv2 += __shfl_xor(qv2, 16); qv2 += __shfl_xor(qv2, 32);
    qv3 += __shfl_xor(qv3, 16); qv3 += __shfl_xor(qv3, 32);
    if ((lane >> 4) == 0) {
        lsum[wv][cc * 4 + 0] = sv0; lsum[wv][cc * 4 + 1] = sv1;
        lsum[wv][cc * 4 + 2] = sv2; lsum[wv][cc * 4 + 3] = sv3;
        lsq[wv][cc * 4 + 0] = qv0; lsq[wv][cc * 4 + 1] = qv1;
        lsq[wv][cc * 4 + 2] = qv2; lsq[wv][cc * 4 + 3] = qv3;
    }
    __syncthreads();
    if (wv == 0) {
        int d = lane;
        float S = lsum[0][d] + lsum[1][d] + lsum[2][d] + lsum[3][d];
        float Q = lsq[0][d] + lsq[1][d] + lsq[2][d] + lsq[3][d];
        atomicAdd(&sums[d], S);
        atomicAdd(&sumsq[d], Q);
    }
}

// ---------------- BN params ----------------
__global__ void k_bn_params(const float* __restrict__ sums, const float* __restrict__ sumsq,
                            const float* __restrict__ g, const float* __restrict__ be,
                            float* __restrict__ scale, float* __restrict__ shift) {
    int d = threadIdx.x;
    if (d >= HID) return;
    float mu  = sums[d] * (1.f / N_NODES);
    float var = sumsq[d] * (1.f / N_NODES) - mu * mu;
    float sc  = g[d] * rsqrtf(var + BN_EPS);
    scale[d] = sc;
    shift[d] = be[d] - mu * sc;
}

// ---------------- act1 = relu(bn1(h1)) materialization (+ zero graph_x) --------
__global__ void k_act(const ushort* __restrict__ h, const float* __restrict__ scale,
                      const float* __restrict__ shift, ushort* __restrict__ act,
                      float* __restrict__ graph_x) {
    if (blockIdx.x == 0) {
        for (int j = threadIdx.x; j < NGRAPH * HID; j += 256) graph_x[j] = 0.f;
    }
    int t = blockIdx.x * blockDim.x + threadIdx.x;   // over N*16
    if (t >= N_NODES * 16) return;
    int q = t & 15;
    uint2 u = *(const uint2*)&h[(size_t)t * 4];
    float4 sc = *(const float4*)&scale[q * 4];
    float4 sh = *(const float4*)&shift[q * 4];
    float f0 = fmaxf(fmaf(bf2f(u.x & 0xFFFFu), sc.x, sh.x), 0.f);
    float f1 = fmaxf(fmaf(bf2f(u.x >> 16),     sc.y, sh.y), 0.f);
    float f2 = fmaxf(fmaf(bf2f(u.y & 0xFFFFu), sc.z, sh.z), 0.f);
    float f3 = fmaxf(fmaf(bf2f(u.y >> 16),     sc.w, sh.w), 0.f);
    uint2 o;
    o.x = f2bf_rtn(f0) | (f2bf_rtn(f1) << 16);
    o.y = f2bf_rtn(f2) | (f2bf_rtn(f3) << 16);
    *(uint2*)&act[(size_t)t * 4] = o;
}

// ---------------- layer-2 gather: mean of act1[src] -> bf16 ----------------
// 512 threads (8 waves), 2 nodes per wave: shorter serial chain, 2x waves.
// Same XCD-aligned bijective block->chunk16 map (grid 8*784=6272).
__global__ __launch_bounds__(512) void k_gather2(
    const ushort* __restrict__ act1b, const int* __restrict__ row_ptr,
    const int* __restrict__ csr_src, ushort* __restrict__ meanb) {
    int c = blockIdx.x;
    int x = c & 7, m = c >> 3;
    int blk = x + 8 * (m >> 3);
    if (blk >= NBLK_G2) return;
    int chunk16 = 8 * blk + (m & 7);
    if (chunk16 >= NTILES) return;
    int lane = threadIdx.x & 63, wv = threadIdx.x >> 6;   // wv 0..7
    int g = lane >> 3, cc = lane & 7;       // dims 8cc..8cc+7
    const uint4* x4 = (const uint4*)act1b;
    uint4* mb4 = (uint4*)meanb;
    #pragma unroll
    for (int n = 0; n < 2; ++n) {
        int node = chunk16 * 16 + wv * 2 + n;
        int beg = row_ptr[node], end = row_ptr[node + 1];
        int deg = end - beg;
        float a0 = 0, a1 = 0, a2 = 0, a3 = 0, a4 = 0, a5 = 0, a6 = 0, a7 = 0;
        float b0 = 0, b1 = 0, b2 = 0, b3 = 0, b4 = 0, b5 = 0, b6 = 0, b7 = 0;
        int iters = (deg + 15) >> 4;
        for (int it = 0; it < iters; ++it) {
            int ea = beg + it * 16 + g;
            int eb = ea + 8;
            if (ea < end) {
                int sn = csr_src[ea];
                uint4 u = x4[(size_t)sn * 8 + cc];
                a0 += bf2f(u.x & 0xFFFFu);
                a1 += bf2f(u.x >> 16);
                a2 += bf2f(u.y & 0xFFFFu);
                a3 += bf2f(u.y >> 16);
                a4 += bf2f(u.z & 0xFFFFu);
                a5 += bf2f(u.z >> 16);
                a6 += bf2f(u.w & 0xFFFFu);
                a7 += bf2f(u.w >> 16);
            }
            if (eb < end) {
                int sn = csr_src[eb];
                uint4 u = x4[(size_t)sn * 8 + cc];
                b0 += bf2f(u.x & 0xFFFFu);
                b1 += bf2f(u.x >> 16);
                b2 += bf2f(u.y & 0xFFFFu);
                b3 += bf2f(u.y >> 16);
                b4 += bf2f(u.z & 0xFFFFu);
                b5 += bf2f(u.z >> 16);
                b6 += bf2f(u.w & 0xFFFFu);
                b7 += bf2f(u.w >> 16);
            }
        }
        a0 += b0; a1 += b1; a2 += b2; a3 += b3;
        a4 += b4; a5 += b5; a6 += b6; a7 += b7;
        #pragma unroll
        for (int off = 8; off < 64; off <<= 1) {
            a0 += __shfl_xor(a0, off); a1 += __shfl_xor(a1, off);
            a2 += __shfl_xor(a2, off); a3 += __shfl_xor(a3, off);
            a4 += __shfl_xor(a4, off); a5 += __shfl_xor(a5, off);
            a6 += __shfl_xor(a6, off); a7 += __shfl_xor(a7, off);
        }
        if (lane < 8) {
            float inv = 1.f / (float)max(deg, 1);
            uint4 o;
            o.x = f2bf_rtn(a0 * inv) | (f2bf_rtn(a1 * inv) << 16);
            o.y = f2bf_rtn(a2 * inv) | (f2bf_rtn(a3 * inv) << 16);
            o.z = f2bf_rtn(a4 * inv) | (f2bf_rtn(a5 * inv) << 16);
            o.w = f2bf_rtn(a6 * inv) | (f2bf_rtn(a7 * inv) << 16);
            mb4[(size_t)node * 8 + lane] = o;
        }
    }
}

// ---------------- pack layer-2 weights into MFMA B-fragments ----------------
__global__ void k_wpack(const float* __restrict__ Wl, const float* __restrict__ Wr,
                        ushort* __restrict__ wpk) {
    int gid = blockIdx.x * blockDim.x + threadIdx.x;   // 1024
    if (gid >= 1024) return;
    int tile = gid >> 6;       // 0..15 = nt*4+kt
    int lane = gid & 63;
    int nt = tile >> 2, kt = tile & 3;
    #pragma unroll
    for (int j = 0; j < 8; ++j) {
        int k = kt * 32 + (lane >> 4) * 8 + j;
        int n = nt * 16 + (lane & 15);
        float v = (k < 64) ? Wl[k * HID + n] : Wr[(k - 64) * HID + n];
        wpk[(size_t)(tile * 64 + lane) * 8 + j] = (ushort)f2bf_rtn(v);
    }
}

// ---------------- layer-2 MFMA: 2 tiles/wave, pure bf16 A loads ----------------
__global__ __launch_bounds__(256) void k_gemm2(
    const ushort* __restrict__ meanb, const ushort* __restrict__ act1b,
    const ushort* __restrict__ wpk, const float* __restrict__ bias,
    ushort* __restrict__ hout, float* __restrict__ sums, float* __restrict__ sumsq) {
    __shared__ float lsum[4][64];
    __shared__ float lsq[4][64];
    int lane = threadIdx.x & 63;
    int wv = threadIdx.x >> 6;
    int r16 = lane & 15;
    int grp = lane >> 4;
    short8 bfrag[4][4];
    const short8* wp = (const short8*)wpk;
    #pragma unroll
    for (int nt = 0; nt < 4; ++nt)
        #pragma unroll
        for (int kt = 0; kt < 4; ++kt)
            bfrag[nt][kt] = wp[(nt * 4 + kt) * 64 + lane];
    float bcol[4];
    #pragma unroll
    for (int nt = 0; nt < 4; ++nt) bcol[nt] = bias[nt * 16 + r16];

    int tbase = (blockIdx.x * 4 + wv) * 2;
    int t0 = tbase, t1 = tbase + 1;
    bool v0 = t0 < NTILES, v1 = t1 < NTILES;

    short8 a0arr[4], a1arr[4];
    if (v0) {
        int node = t0 * 16 + r16;
        const short8* mrow = (const short8*)(meanb + (size_t)node * HID);
        const short8* srow = (const short8*)(act1b + (size_t)node * HID);
        a0arr[0] = mrow[grp];
        a0arr[1] = mrow[4 + grp];
        a0arr[2] = srow[grp];
        a0arr[3] = srow[4 + grp];
    }
    if (v1) {
        int node = t1 * 16 + r16;
        const short8* mrow = (const short8*)(meanb + (size_t)node * HID);
        const short8* srow = (const short8*)(act1b + (size_t)node * HID);
        a1arr[0] = mrow[grp];
        a1arr[1] = mrow[4 + grp];
        a1arr[2] = srow[grp];
        a1arr[3] = srow[4 + grp];
    }

    float sv[4] = {0.f, 0.f, 0.f, 0.f}, qv[4] = {0.f, 0.f, 0.f, 0.f};

    #pragma unroll
    for (int j = 0; j < 2; ++j) {
        bool valid = j == 0 ? v0 : v1;
        if (!valid) continue;
        int tile = j == 0 ? t0 : t1;
        short8* a = j == 0 ? a0arr : a1arr;
        f32x4 acc[4];
        #pragma unroll
        for (int nt = 0; nt < 4; ++nt) acc[nt] = (f32x4){0.f, 0.f, 0.f, 0.f};
        #pragma unroll
        for (int nt = 0; nt < 4; ++nt)
            #pragma unroll
            for (int kt = 0; kt < 4; ++kt)
                acc[nt] = __builtin_amdgcn_mfma_f32_16x16x32_bf16(a[kt], bfrag[nt][kt],
                                                                  acc[nt], 0, 0, 0);
        #pragma unroll
        for (int nt = 0; nt < 4; ++nt) {
            #pragma unroll
            for (int r = 0; r < 4; ++r) {
                float hv = acc[nt][r] + bcol[nt];
                int rrow = tile * 16 + grp * 4 + r;
                hout[(size_t)rrow * HID + nt * 16 + r16] = (ushort)f2bf_rtn(hv);
                sv[nt] += hv;
                qv[nt] += hv * hv;
            }
        }
    }
    #pragma unroll
    for (int nt = 0; nt < 4; ++nt) {
        float v = sv[nt];
        v += __shfl_xor(v, 16); v += __shfl_xor(v, 32);
        float q = qv[nt];
        q += __shfl_xor(q, 16); q += __shfl_xor(q, 32);
        if (grp == 0) {
            lsum[wv][nt * 16 + r16] = v;
            lsq[wv][nt * 16 + r16] = q;
        }
    }
    __syncthreads();
    if (wv == 0) {
        int d = lane;
        float S = lsum[0][d] + lsum[1][d] + lsum[2][d] + lsum[3][d];
        float Q = lsq[0][d] + lsq[1][d] + lsq[2][d] + lsq[3][d];
        atomicAdd(&sums[d], S);
        atomicAdd(&sumsq[d], Q);
    }
}

// ---------------- pool (fused bn2+relu, bf16 in) + classifier ----------------
__global__ __launch_bounds__(256) void k_pool(const ushort* __restrict__ h,
                                              const int* __restrict__ batch,
                                              const float* __restrict__ scale,
                                              const float* __restrict__ shift,
                                              float* __restrict__ graph_x) {
    int wv = threadIdx.x >> 6, d = threadIdx.x & 63;
    float sc = scale[d], sh = shift[d];
    const int NCHUNK = 4096;
    int cidx = blockIdx.x * 4 + wv;
    int chunk = (N_NODES + NCHUNK - 1) / NCHUNK;   // 25
    int a = cidx * chunk;
    int b = min(a + chunk, N_NODES);
    if (a >= b) return;
    int cur = batch[a];
    float acc = 0.f;
    for (int i = a; i < b; ++i) {
        int g = batch[i];
        if (g != cur) {
            atomicAdd(&graph_x[cur * HID + d], acc);
            acc = 0.f;
            cur = g;
        }
        float v = bf2f((uint32_t)h[(size_t)i * HID + d]);
        acc += fmaxf(fmaf(v, sc, sh), 0.f);
    }
    atomicAdd(&graph_x[cur * HID + d], acc);
}

__global__ void k_cls(const float* __restrict__ graph_x, const float* __restrict__ Wlin,
                      const float* __restrict__ blin, float* __restrict__ out) {
    int idx = blockIdx.x * blockDim.x + threadIdx.x;
    if (idx >= NGRAPH * NCLS) return;
    int g = idx / NCLS, c = idx % NCLS;
    float acc = blin[c];
    #pragma unroll
    for (int k = 0; k < HID; ++k) acc += graph_x[g * HID + k] * Wlin[k * NCLS + c];
    out[idx] = acc;
}

// ---------------- launch ----------------
extern "C" void kernel_launch(void* const* d_in, const int* in_sizes, int n_in,
                              void* d_out, int out_size, void* d_ws, size_t ws_size,
                              hipStream_t stream) {
    const int*   sid   = (const int*)d_in[0];
    const int*   cid   = (const int*)d_in[1];
    const int*   esrc  = (const int*)d_in[2];
    const int*   edst  = esrc + N_EDGES;
    const int*   batch = (const int*)d_in[3];
    const float* sW    = (const float*)d_in[4];
    const float* cW    = (const float*)d_in[5];
    const float* W1l   = (const float*)d_in[6];
    const float* b1    = (const float*)d_in[7];
    const float* W1r   = (const float*)d_in[8];
    const float* g1    = (const float*)d_in[9];
    const float* be1   = (const float*)d_in[10];
    const float* W2l   = (const float*)d_in[11];
    const float* b2    = (const float*)d_in[12];
    const float* W2r   = (const float*)d_in[13];
    const float* g2    = (const float*)d_in[14];
    const float* be2   = (const float*)d_in[15];
    const float* Wlin  = (const float*)d_in[16];
    const float* blin  = (const float*)d_in[17];
    float* out = (float*)d_out;

    // workspace layout
    const size_t FEAT = (size_t)N_NODES * HID;        // elements (ushort)
    ushort* scratch = (ushort*)d_ws;                  // staged32 alias, then meanb
    ushort* h1b   = scratch + FEAT;                   // raw h1 bf16
    ushort* act1b = h1b + FEAT;                       // relu(bn1(h1)) bf16
    ushort* h2b   = act1b + FEAT;                     // raw h2 bf16
    ushort* wpk2  = h2b + FEAT;                       // 8192 (16 frag tiles)
    ushort* tblR  = wpk2 + 8192;                      // 128*64 bf16
    float* TsL    = (float*)(tblR + 8192);            // 24*64 f32
    float* fp     = TsL + 24 * 64;
    float* sums1  = fp;            float* sumsq1 = sums1 + HID;
    float* sums2  = sumsq1 + HID;  float* sumsq2 = sums2 + HID;
    float* scale1 = sumsq2 + HID;  float* shift1 = scale1 + HID;
    float* scale2 = shift1 + HID;  float* shift2 = scale2 + HID;
    float* graph_x = shift2 + HID;                    // NGRAPH*HID
    int* row_ptr  = (int*)(graph_x + (size_t)NGRAPH * HID);   // N+1
    int* csr_src  = row_ptr + N_NODES + 1;                    // E
    int* bucket_cnt = csr_src + N_EDGES;                      // NB
    int* bucket_off = bucket_cnt + NB;                        // NB+1
    unsigned char* code8 = (unsigned char*)(bucket_off + NB + 1);  // N bytes
    uint32_t* staged = (uint32_t*)scratch;            // NB*BKT_CAP*4B = 6.38MB
    ushort* meanb = scratch;                          // reused after k_place

    // ---- precompute: codes (+zero accumulators), layer-1 tables, wpk2 ----
    k_code<<<(N_NODES + 255) / 256, 256, 0, stream>>>(sid, cid, code8,
                                                      bucket_cnt, sums1);
    k_tab<<<38, 256, 0, stream>>>(sW, cW, W1l, W1r, b1, TsL, tblR);
    k_wpack<<<4, 256, 0, stream>>>(W2l, W2r, wpk2);

    // ---- bucket CSR build; k_place fuses layer-1 h1 computation ----
    k_bucket<<<NBLK_E, 256, 0, stream>>>(esrc, edst, code8, bucket_cnt, staged);
    k_bscan<<<1, 512, 0, stream>>>(bucket_cnt, bucket_off, row_ptr);
    k_place<<<NB, 256, 0, stream>>>(staged, bucket_off, code8, TsL, tblR,
                                    row_ptr, csr_src, h1b, sums1, sumsq1);
    k_bn_params<<<1, 64, 0, stream>>>(sums1, sumsq1, g1, be1, scale1, shift1);

    // ---- act1 materialization (+ zero graph_x) ----
    k_act<<<(N_NODES * 16 + 255) / 256, 256, 0, stream>>>(h1b, scale1, shift1,
                                                          act1b, graph_x);

    // ---- layer 2 (XCD-aligned gather, 8 waves/block -> batched MFMA) ----
    k_gather2<<<8 * 784, 512, 0, stream>>>(act1b, row_ptr, csr_src, meanb);
    k_gemm2<<<NBLK_G2, 256, 0, stream>>>(meanb, act1b, wpk2, b2,
                                         h2b, sums2, sumsq2);
    k_bn_params<<<1, 64, 0, stream>>>(sums2, sumsq2, g2, be2, scale2, shift2);

    // ---- pool (fused bn2+relu) + classifier ----
    k_pool<<<1024, 256, 0, stream>>>(h2b, batch, scale2, shift2, graph_x);
    k_cls<<<(NGRAPH * NCLS + 255) / 256, 256, 0, stream>>>(graph_x, Wlin, blin, out);
}

// Round 22
// 158.919 us; speedup vs baseline: 1.0254x; 1.0254x over previous
//
#include <hip/hip_runtime.h>
#include <stdint.h>

#define N_NODES 100000
#define N_EDGES 1200000
#define HID 64
#define NGRAPH 512
#define NCLS 2
#define BN_EPS 1e-5f

#define NTILES (N_NODES / 16)     // 6250, exact
#define NBLK_G2 782               // ceil(6250/8) — gemm2 grid (2 tiles/wave, 4 waves)

// bucket sort: 256-node buckets, fixed-capacity staging (uint32: code|src|dstl)
#define BKT_SH 8
#define BKT_NODES 256
#define NB 391                     // ceil(100000/256)
#define BKT_CAP 4080               // mean 3069 + 18 sigma; 391*4080*4B = 6.38MB
#define EB_PER_BLK 4096            // edges per k_bucket block (256 thr x 16)
#define NBLK_E 293                 // ceil(1200000/4096)

typedef __attribute__((ext_vector_type(8))) short short8;   // 8 bf16 = 4 VGPRs
typedef __attribute__((ext_vector_type(4))) float f32x4;

__device__ inline float bf2f(uint32_t hi16) {
    uint32_t u = hi16 << 16;
    return __builtin_bit_cast(float, u);
}
__device__ inline uint32_t f2bf_rtn(float f) {             // round-to-nearest-even
    uint32_t u = __builtin_bit_cast(uint32_t, f);
    return (u + 0x7FFFu + ((u >> 16) & 1u)) >> 16;
}

// ---------------- node code + zero accumulators (replaces memsets) ----------------
__global__ void k_code(const int* __restrict__ sid, const int* __restrict__ cid,
                       unsigned char* __restrict__ code8,
                       int* __restrict__ bucket_cnt, float* __restrict__ stats) {
    int i = blockIdx.x * blockDim.x + threadIdx.x;
    if (i < N_NODES) code8[i] = (unsigned char)(sid[i] | (cid[i] << 4));
    if (blockIdx.x == 0) {
        for (int j = threadIdx.x; j < NB; j += 256) bucket_cnt[j] = 0;
        for (int j = threadIdx.x; j < 4 * HID; j += 256) stats[j] = 0.f;
    }
}

// ---------------- layer-1 tables + layer-2 weight pack (merged) ----------------
// TsL[24][64] f32; tblR[128][64] bf16; wpk (16 frag tiles of W2l;W2r)
__global__ __launch_bounds__(256) void k_tab(const float* __restrict__ sW,
                                             const float* __restrict__ cW,
                                             const float* __restrict__ W1l,
                                             const float* __restrict__ W1r,
                                             const float* __restrict__ b1,
                                             const float* __restrict__ W2l,
                                             const float* __restrict__ W2r,
                                             float* __restrict__ TsL,
                                             ushort* __restrict__ tblR,
                                             ushort* __restrict__ wpk) {
    int gid = blockIdx.x * 256 + threadIdx.x;
    if (gid < 24 * 64) {
        int row = gid >> 6, d = gid & 63;
        const float* e = (row < 16) ? &sW[row * 64] : &cW[(row - 16) * 64];
        float acc = 0.f;
        #pragma unroll 8
        for (int k = 0; k < 64; ++k) acc += e[k] * W1l[k * 64 + d];
        TsL[gid] = acc;
    } else if (gid < 24 * 64 + 128 * 64) {
        int r = gid - 24 * 64;
        int c = r >> 6, d = r & 63;
        int s = c & 15, cl = c >> 4;
        float acc = b1[d];
        #pragma unroll 8
        for (int k = 0; k < 64; ++k)
            acc += (sW[s * 64 + k] + cW[cl * 64 + k]) * W1r[k * 64 + d];
        tblR[r] = (ushort)f2bf_rtn(acc);
    } else if (gid < 24 * 64 + 128 * 64 + 1024) {
        int g2 = gid - (24 * 64 + 128 * 64);
        int tile = g2 >> 6;        // 0..15 = nt*4+kt
        int lane = g2 & 63;
        int nt = tile >> 2, kt = tile & 3;
        #pragma unroll
        for (int j = 0; j < 8; ++j) {
            int k = kt * 32 + (lane >> 4) * 8 + j;
            int n = nt * 16 + (lane & 15);
            float v = (k < 64) ? W2l[k * HID + n] : W2r[(k - 64) * HID + n];
            wpk[(size_t)(tile * 64 + lane) * 8 + j] = (ushort)f2bf_rtn(v);
        }
    }
}

// ---------------- bucket CSR build: pack code|src|dstl in uint32 staged --------
__global__ __launch_bounds__(256) void k_bucket(const int* __restrict__ src,
                                                const int* __restrict__ dst,
                                                const unsigned char* __restrict__ code8,
                                                int* __restrict__ bucket_cnt,
                                                uint32_t* __restrict__ staged) {
    __shared__ int h[NB];
    __shared__ int cur[NB];
    int tid = threadIdx.x;
    for (int j = tid; j < NB; j += 256) h[j] = 0;
    __syncthreads();
    uint32_t pk[16];
    int bk[16];
    int base = blockIdx.x * EB_PER_BLK;
    #pragma unroll
    for (int i = 0; i < 16; ++i) {
        int e = base + i * 256 + tid;
        if (e < N_EDGES) {
            int s = src[e], d = dst[e];
            int c = code8[s];
            bk[i] = d >> BKT_SH;
            pk[i] = ((uint32_t)c << 25) | ((uint32_t)s << 8)
                  | (uint32_t)(d & (BKT_NODES - 1));
            atomicAdd(&h[bk[i]], 1);
        } else {
            bk[i] = -1;
        }
    }
    __syncthreads();
    for (int j = tid; j < NB; j += 256)
        cur[j] = (h[j] > 0) ? atomicAdd(&bucket_cnt[j], h[j]) : 0;
    __syncthreads();
    #pragma unroll
    for (int i = 0; i < 16; ++i) {
        if (bk[i] >= 0) {
            int slot = atomicAdd(&cur[bk[i]], 1);
            staged[(size_t)bk[i] * BKT_CAP + slot] = pk[i];
        }
    }
}

// scan NB bucket counts -> bucket_off (global csr offsets)
__global__ __launch_bounds__(512) void k_bscan(const int* __restrict__ bucket_cnt,
                                               int* __restrict__ bucket_off,
                                               int* __restrict__ row_ptr) {
    __shared__ int sh[512];
    int t = threadIdx.x;
    int v = (t < NB) ? bucket_cnt[t] : 0;
    sh[t] = v;
    __syncthreads();
    #pragma unroll
    for (int off = 1; off < 512; off <<= 1) {
        int cur = sh[t];
        int u = (t >= off) ? sh[t - off] : 0;
        __syncthreads();
        sh[t] = cur + u;
        __syncthreads();
    }
    if (t < NB) bucket_off[t] = sh[t] - v;
    if (t == 0) {
        bucket_off[NB] = N_EDGES;
        row_ptr[N_NODES] = N_EDGES;
    }
}

// ---------------- place + histogram + fused layer-1 (256-node buckets) ----------
__global__ __launch_bounds__(256) void k_place(const uint32_t* __restrict__ staged,
                                               const int* __restrict__ bucket_off,
                                               const unsigned char* __restrict__ code8,
                                               const float* __restrict__ TsL,
                                               const ushort* __restrict__ tblR,
                                               int* __restrict__ row_ptr,
                                               int* __restrict__ csr_src,
                                               ushort* __restrict__ h1b,
                                               float* __restrict__ sums,
                                               float* __restrict__ sumsq) {
    __shared__ int hist[BKT_NODES];
    __shared__ int cursor[BKT_NODES];
    __shared__ int part[256];
    __shared__ int cnt24[BKT_NODES * 12];   // 12 KB
    __shared__ float lsum[4][64];
    __shared__ float lsq[4][64];
    int b = blockIdx.x;
    int tid = threadIdx.x;
    int lane = tid & 63, wv = tid >> 6;
    int cc = tid & 15;
    int nodes0 = b << BKT_SH;
    int nn = min(BKT_NODES, N_NODES - nodes0);
    int ebeg = bucket_off[b];
    int cntb = bucket_off[b + 1] - ebeg;
    const uint32_t* st = &staged[(size_t)b * BKT_CAP];

    f32x4 trow[24];
    #pragma unroll
    for (int s = 0; s < 24; ++s)
        trow[s] = *(const f32x4*)&TsL[s * 64 + cc * 4];

    hist[tid] = 0;
    #pragma unroll
    for (int j = 0; j < 12; ++j) cnt24[tid * 12 + j] = 0;
    __syncthreads();
    for (int e = tid; e < cntb; e += 256)
        atomicAdd(&hist[(int)(st[e] & (BKT_NODES - 1))], 1);
    __syncthreads();
    int myc = hist[tid];
    part[tid] = myc;
    __syncthreads();
    #pragma unroll
    for (int off = 1; off < 256; off <<= 1) {
        int curv = part[tid];
        int u = (tid >= off) ? part[tid - off] : 0;
        __syncthreads();
        part[tid] = curv + u;
        __syncthreads();
    }
    int ex = ebeg + part[tid] - myc;
    cursor[tid] = ex;
    if (tid < nn) row_ptr[nodes0 + tid] = ex;
    __syncthreads();
    for (int e = tid; e < cntb; e += 256) {
        uint32_t pk = st[e];
        int nl = (int)(pk & (BKT_NODES - 1));
        int slot = atomicAdd(&cursor[nl], 1);
        csr_src[slot] = (int)((pk >> 8) & 0x1FFFFu);
        int c = (int)(pk >> 25);
        int sb = c & 15, cb = c >> 4;
        atomicAdd(&cnt24[nl * 12 + (sb >> 1)], 1 << ((sb & 1) * 16));
        atomicAdd(&cnt24[nl * 12 + 8 + (cb >> 1)], 1 << ((cb & 1) * 16));
    }
    __syncthreads();

    float sv0 = 0, sv1 = 0, sv2 = 0, sv3 = 0;
    float qv0 = 0, qv1 = 0, qv2 = 0, qv3 = 0;
    int nrow = tid >> 4;                     // 0..15
    for (int it = 0; it < 16; ++it) {
        int nl = it * 16 + nrow;
        if (nl >= nn) continue;
        int node = nodes0 + nl;
        int cw[12];
        *(uint4*)&cw[0] = *(const uint4*)&cnt24[nl * 12];
        *(uint4*)&cw[4] = *(const uint4*)&cnt24[nl * 12 + 4];
        *(uint4*)&cw[8] = *(const uint4*)&cnt24[nl * 12 + 8];
        int deg = hist[nl];
        float a0 = 0, a1 = 0, a2 = 0, a3 = 0;
        #pragma unroll
        for (int ss = 0; ss < 24; ++ss) {
            int j = (ss < 16) ? (ss >> 1) : (8 + ((ss - 16) >> 1));
            float w = (float)((cw[j] >> ((ss & 1) * 16)) & 0xFFFF);
            a0 += w * trow[ss].x; a1 += w * trow[ss].y;
            a2 += w * trow[ss].z; a3 += w * trow[ss].w;
        }
        float inv = 1.f / (float)max(deg, 1);
        int ci = code8[node];
        uint2 trv = *(const uint2*)&tblR[ci * 64 + cc * 4];
        float h0 = fmaf(a0, inv, bf2f(trv.x & 0xFFFFu));
        float h1 = fmaf(a1, inv, bf2f(trv.x >> 16));
        float h2 = fmaf(a2, inv, bf2f(trv.y & 0xFFFFu));
        float h3 = fmaf(a3, inv, bf2f(trv.y >> 16));
        uint2 o;
        o.x = f2bf_rtn(h0) | (f2bf_rtn(h1) << 16);
        o.y = f2bf_rtn(h2) | (f2bf_rtn(h3) << 16);
        *(uint2*)&h1b[(size_t)node * HID + cc * 4] = o;
        sv0 += h0; qv0 += h0 * h0;
        sv1 += h1; qv1 += h1 * h1;
        sv2 += h2; qv2 += h2 * h2;
        sv3 += h3; qv3 += h3 * h3;
    }
    sv0 += __shfl_xor(sv0, 16); sv0 += __shfl_xor(sv0, 32);
    sv1 += __shfl_xor(sv1, 16); sv1 += __shfl_xor(sv1, 32);
    sv2 += __shfl_xor(sv2, 16); sv2 += __shfl_xor(sv2, 32);
    sv3 += __shfl_xor(sv3, 16); sv3 += __shfl_xor(sv3, 32);
    qv0 += __shfl_xor(qv0, 16); qv0 += __shfl_xor(qv0, 32);
    qv1 += __shfl_xor(qv1, 16); qv1 += __shfl_xor(qv1, 32);
    qv2 += __shfl_xor(qv2, 16); qv2 += __shfl_xor(qv2, 32);
    qv3 += __shfl_xor(qv3, 16); qv3 += __shfl_xor(qv3, 32);
    if ((lane >> 4) == 0) {
        lsum[wv][cc * 4 + 0] = sv0; lsum[wv][cc * 4 + 1] = sv1;
        lsum[wv][cc * 4 + 2] = sv2; lsum[wv][cc * 4 + 3] = sv3;
        lsq[wv][cc * 4 + 0] = qv0; lsq[wv][cc * 4 + 1] = qv1;
        lsq[wv][cc * 4 + 2] = qv2; lsq[wv][cc * 4 + 3] = qv3;
    }
    __syncthreads();
    if (wv == 0) {
        int d = lane;
        float S = lsum[0][d] + lsum[1][d] + lsum[2][d] + lsum[3][d];
        float Q = lsq[0][d] + lsq[1][d] + lsq[2][d] + lsq[3][d];
        atomicAdd(&sums[d], S);
        atomicAdd(&sumsq[d], Q);
    }
}

// ---------------- act1 = relu(bn1(h1)), BN params inlined (+ zero graph_x) -----
__global__ void k_act(const ushort* __restrict__ h,
                      const float* __restrict__ sums, const float* __restrict__ sumsq,
                      const float* __restrict__ g1, const float* __restrict__ be1,
                      ushort* __restrict__ act, float* __restrict__ graph_x) {
    if (blockIdx.x == 0) {
        for (int j = threadIdx.x; j < NGRAPH * HID; j += 256) graph_x[j] = 0.f;
    }
    int t = blockIdx.x * blockDim.x + threadIdx.x;   // over N*16
    if (t >= N_NODES * 16) return;
    int q = t & 15;
    float4 sc, sh;
    {
        const float invn = 1.f / N_NODES;
        #pragma unroll
        for (int j = 0; j < 4; ++j) {
            int d = q * 4 + j;
            float mu  = sums[d] * invn;
            float var = sumsq[d] * invn - mu * mu;
            float s   = g1[d] * rsqrtf(var + BN_EPS);
            ((float*)&sc)[j] = s;
            ((float*)&sh)[j] = be1[d] - mu * s;
        }
    }
    uint2 u = *(const uint2*)&h[(size_t)t * 4];
    float f0 = fmaxf(fmaf(bf2f(u.x & 0xFFFFu), sc.x, sh.x), 0.f);
    float f1 = fmaxf(fmaf(bf2f(u.x >> 16),     sc.y, sh.y), 0.f);
    float f2 = fmaxf(fmaf(bf2f(u.y & 0xFFFFu), sc.z, sh.z), 0.f);
    float f3 = fmaxf(fmaf(bf2f(u.y >> 16),     sc.w, sh.w), 0.f);
    uint2 o;
    o.x = f2bf_rtn(f0) | (f2bf_rtn(f1) << 16);
    o.y = f2bf_rtn(f2) | (f2bf_rtn(f3) << 16);
    *(uint2*)&act[(size_t)t * 4] = o;
}

// ---------------- layer-2 gather: mean of act1[src] -> bf16 ----------------
// 512 threads (8 waves), 2 nodes per wave; XCD-aligned bijective map.
__global__ __launch_bounds__(512) void k_gather2(
    const ushort* __restrict__ act1b, const int* __restrict__ row_ptr,
    const int* __restrict__ csr_src, ushort* __restrict__ meanb) {
    int c = blockIdx.x;
    int x = c & 7, m = c >> 3;
    int blk = x + 8 * (m >> 3);
    if (blk >= NBLK_G2) return;
    int chunk16 = 8 * blk + (m & 7);
    if (chunk16 >= NTILES) return;
    int lane = threadIdx.x & 63, wv = threadIdx.x >> 6;   // wv 0..7
    int g = lane >> 3, cc = lane & 7;       // dims 8cc..8cc+7
    const uint4* x4 = (const uint4*)act1b;
    uint4* mb4 = (uint4*)meanb;
    #pragma unroll
    for (int n = 0; n < 2; ++n) {
        int node = chunk16 * 16 + wv * 2 + n;
        int beg = row_ptr[node], end = row_ptr[node + 1];
        int deg = end - beg;
        float a0 = 0, a1 = 0, a2 = 0, a3 = 0, a4 = 0, a5 = 0, a6 = 0, a7 = 0;
        float b0 = 0, b1 = 0, b2 = 0, b3 = 0, b4 = 0, b5 = 0, b6 = 0, b7 = 0;
        int iters = (deg + 15) >> 4;
        for (int it = 0; it < iters; ++it) {
            int ea = beg + it * 16 + g;
            int eb = ea + 8;
            if (ea < end) {
                int sn = csr_src[ea];
                uint4 u = x4[(size_t)sn * 8 + cc];
                a0 += bf2f(u.x & 0xFFFFu);
                a1 += bf2f(u.x >> 16);
                a2 += bf2f(u.y & 0xFFFFu);
                a3 += bf2f(u.y >> 16);
                a4 += bf2f(u.z & 0xFFFFu);
                a5 += bf2f(u.z >> 16);
                a6 += bf2f(u.w & 0xFFFFu);
                a7 += bf2f(u.w >> 16);
            }
            if (eb < end) {
                int sn = csr_src[eb];
                uint4 u = x4[(size_t)sn * 8 + cc];
                b0 += bf2f(u.x & 0xFFFFu);
                b1 += bf2f(u.x >> 16);
                b2 += bf2f(u.y & 0xFFFFu);
                b3 += bf2f(u.y >> 16);
                b4 += bf2f(u.z & 0xFFFFu);
                b5 += bf2f(u.z >> 16);
                b6 += bf2f(u.w & 0xFFFFu);
                b7 += bf2f(u.w >> 16);
            }
        }
        a0 += b0; a1 += b1; a2 += b2; a3 += b3;
        a4 += b4; a5 += b5; a6 += b6; a7 += b7;
        #pragma unroll
        for (int off = 8; off < 64; off <<= 1) {
            a0 += __shfl_xor(a0, off); a1 += __shfl_xor(a1, off);
            a2 += __shfl_xor(a2, off); a3 += __shfl_xor(a3, off);
            a4 += __shfl_xor(a4, off); a5 += __shfl_xor(a5, off);
            a6 += __shfl_xor(a6, off); a7 += __shfl_xor(a7, off);
        }
        if (lane < 8) {
            float inv = 1.f / (float)max(deg, 1);
            uint4 o;
            o.x = f2bf_rtn(a0 * inv) | (f2bf_rtn(a1 * inv) << 16);
            o.y = f2bf_rtn(a2 * inv) | (f2bf_rtn(a3 * inv) << 16);
            o.z = f2bf_rtn(a4 * inv) | (f2bf_rtn(a5 * inv) << 16);
            o.w = f2bf_rtn(a6 * inv) | (f2bf_rtn(a7 * inv) << 16);
            mb4[(size_t)node * 8 + lane] = o;
        }
    }
}

// ---------------- layer-2 MFMA: 2 tiles/wave, pure bf16 A loads ----------------
__global__ __launch_bounds__(256) void k_gemm2(
    const ushort* __restrict__ meanb, const ushort* __restrict__ act1b,
    const ushort* __restrict__ wpk, const float* __restrict__ bias,
    ushort* __restrict__ hout, float* __restrict__ sums, float* __restrict__ sumsq) {
    __shared__ float lsum[4][64];
    __shared__ float lsq[4][64];
    int lane = threadIdx.x & 63;
    int wv = threadIdx.x >> 6;
    int r16 = lane & 15;
    int grp = lane >> 4;
    short8 bfrag[4][4];
    const short8* wp = (const short8*)wpk;
    #pragma unroll
    for (int nt = 0; nt < 4; ++nt)
        #pragma unroll
        for (int kt = 0; kt < 4; ++kt)
            bfrag[nt][kt] = wp[(nt * 4 + kt) * 64 + lane];
    float bcol[4];
    #pragma unroll
    for (int nt = 0; nt < 4; ++nt) bcol[nt] = bias[nt * 16 + r16];

    int tbase = (blockIdx.x * 4 + wv) * 2;
    int t0 = tbase, t1 = tbase + 1;
    bool v0 = t0 < NTILES, v1 = t1 < NTILES;

    short8 a0arr[4], a1arr[4];
    if (v0) {
        int node = t0 * 16 + r16;
        const short8* mrow = (const short8*)(meanb + (size_t)node * HID);
        const short8* srow = (const short8*)(act1b + (size_t)node * HID);
        a0arr[0] = mrow[grp];
        a0arr[1] = mrow[4 + grp];
        a0arr[2] = srow[grp];
        a0arr[3] = srow[4 + grp];
    }
    if (v1) {
        int node = t1 * 16 + r16;
        const short8* mrow = (const short8*)(meanb + (size_t)node * HID);
        const short8* srow = (const short8*)(act1b + (size_t)node * HID);
        a1arr[0] = mrow[grp];
        a1arr[1] = mrow[4 + grp];
        a1arr[2] = srow[grp];
        a1arr[3] = srow[4 + grp];
    }

    float sv[4] = {0.f, 0.f, 0.f, 0.f}, qv[4] = {0.f, 0.f, 0.f, 0.f};

    #pragma unroll
    for (int j = 0; j < 2; ++j) {
        bool valid = j == 0 ? v0 : v1;
        if (!valid) continue;
        int tile = j == 0 ? t0 : t1;
        short8* a = j == 0 ? a0arr : a1arr;
        f32x4 acc[4];
        #pragma unroll
        for (int nt = 0; nt < 4; ++nt) acc[nt] = (f32x4){0.f, 0.f, 0.f, 0.f};
        #pragma unroll
        for (int nt = 0; nt < 4; ++nt)
            #pragma unroll
            for (int kt = 0; kt < 4; ++kt)
                acc[nt] = __builtin_amdgcn_mfma_f32_16x16x32_bf16(a[kt], bfrag[nt][kt],
                                                                  acc[nt], 0, 0, 0);
        #pragma unroll
        for (int nt = 0; nt < 4; ++nt) {
            #pragma unroll
            for (int r = 0; r < 4; ++r) {
                float hv = acc[nt][r] + bcol[nt];
                int rrow = tile * 16 + grp * 4 + r;
                hout[(size_t)rrow * HID + nt * 16 + r16] = (ushort)f2bf_rtn(hv);
                sv[nt] += hv;
                qv[nt] += hv * hv;
            }
        }
    }
    #pragma unroll
    for (int nt = 0; nt < 4; ++nt) {
        float v = sv[nt];
        v += __shfl_xor(v, 16); v += __shfl_xor(v, 32);
        float q = qv[nt];
        q += __shfl_xor(q, 16); q += __shfl_xor(q, 32);
        if (grp == 0) {
            lsum[wv][nt * 16 + r16] = v;
            lsq[wv][nt * 16 + r16] = q;
        }
    }
    __syncthreads();
    if (wv == 0) {
        int d = lane;
        float S = lsum[0][d] + lsum[1][d] + lsum[2][d] + lsum[3][d];
        float Q = lsq[0][d] + lsq[1][d] + lsq[2][d] + lsq[3][d];
        atomicAdd(&sums[d], S);
        atomicAdd(&sumsq[d], Q);
    }
}

// ---------------- pool (BN2 params inlined + relu) + classifier ----------------
__global__ __launch_bounds__(256) void k_pool(const ushort* __restrict__ h,
                                              const int* __restrict__ batch,
                                              const float* __restrict__ sums,
                                              const float* __restrict__ sumsq,
                                              const float* __restrict__ g2,
                                              const float* __restrict__ be2,
                                              float* __restrict__ graph_x) {
    int wv = threadIdx.x >> 6, d = threadIdx.x & 63;
    float mu  = sums[d] * (1.f / N_NODES);
    float var = sumsq[d] * (1.f / N_NODES) - mu * mu;
    float sc  = g2[d] * rsqrtf(var + BN_EPS);
    float sh  = be2[d] - mu * sc;
    const int NCHUNK = 4096;
    int cidx = blockIdx.x * 4 + wv;
    int chunk = (N_NODES + NCHUNK - 1) / NCHUNK;   // 25
    int a = cidx * chunk;
    int b = min(a + chunk, N_NODES);
    if (a >= b) return;
    int cur = batch[a];
    float acc = 0.f;
    for (int i = a; i < b; ++i) {
        int g = batch[i];
        if (g != cur) {
            atomicAdd(&graph_x[cur * HID + d], acc);
            acc = 0.f;
            cur = g;
        }
        float v = bf2f((uint32_t)h[(size_t)i * HID + d]);
        acc += fmaxf(fmaf(v, sc, sh), 0.f);
    }
    atomicAdd(&graph_x[cur * HID + d], acc);
}

__global__ void k_cls(const float* __restrict__ graph_x, const float* __restrict__ Wlin,
                      const float* __restrict__ blin, float* __restrict__ out) {
    int idx = blockIdx.x * blockDim.x + threadIdx.x;
    if (idx >= NGRAPH * NCLS) return;
    int g = idx / NCLS, c = idx % NCLS;
    float acc = blin[c];
    #pragma unroll
    for (int k = 0; k < HID; ++k) acc += graph_x[g * HID + k] * Wlin[k * NCLS + c];
    out[idx] = acc;
}

// ---------------- launch ----------------
extern "C" void kernel_launch(void* const* d_in, const int* in_sizes, int n_in,
                              void* d_out, int out_size, void* d_ws, size_t ws_size,
                              hipStream_t stream) {
    const int*   sid   = (const int*)d_in[0];
    const int*   cid   = (const int*)d_in[1];
    const int*   esrc  = (const int*)d_in[2];
    const int*   edst  = esrc + N_EDGES;
    const int*   batch = (const int*)d_in[3];
    const float* sW    = (const float*)d_in[4];
    const float* cW    = (const float*)d_in[5];
    const float* W1l   = (const float*)d_in[6];
    const float* b1    = (const float*)d_in[7];
    const float* W1r   = (const float*)d_in[8];
    const float* g1    = (const float*)d_in[9];
    const float* be1   = (const float*)d_in[10];
    const float* W2l   = (const float*)d_in[11];
    const float* b2    = (const float*)d_in[12];
    const float* W2r   = (const float*)d_in[13];
    const float* g2    = (const float*)d_in[14];
    const float* be2   = (const float*)d_in[15];
    const float* Wlin  = (const float*)d_in[16];
    const float* blin  = (const float*)d_in[17];
    float* out = (float*)d_out;

    // workspace layout
    const size_t FEAT = (size_t)N_NODES * HID;        // elements (ushort)
    ushort* scratch = (ushort*)d_ws;                  // staged32 alias, then meanb
    ushort* h1b   = scratch + FEAT;                   // raw h1 bf16
    ushort* act1b = h1b + FEAT;                       // relu(bn1(h1)) bf16
    ushort* h2b   = act1b + FEAT;                     // raw h2 bf16
    ushort* wpk2  = h2b + FEAT;                       // 8192 (16 frag tiles)
    ushort* tblR  = wpk2 + 8192;                      // 128*64 bf16
    float* TsL    = (float*)(tblR + 8192);            // 24*64 f32
    float* fp     = TsL + 24 * 64;
    float* sums1  = fp;            float* sumsq1 = sums1 + HID;
    float* sums2  = sumsq1 + HID;  float* sumsq2 = sums2 + HID;
    float* graph_x = sumsq2 + HID;                    // NGRAPH*HID
    int* row_ptr  = (int*)(graph_x + (size_t)NGRAPH * HID);   // N+1
    int* csr_src  = row_ptr + N_NODES + 1;                    // E
    int* bucket_cnt = csr_src + N_EDGES;                      // NB
    int* bucket_off = bucket_cnt + NB;                        // NB+1
    unsigned char* code8 = (unsigned char*)(bucket_off + NB + 1);  // N bytes
    uint32_t* staged = (uint32_t*)scratch;            // NB*BKT_CAP*4B = 6.38MB
    ushort* meanb = scratch;                          // reused after k_place

    // ---- precompute: codes (+zero accumulators), tables + weight pack ----
    k_code<<<(N_NODES + 255) / 256, 256, 0, stream>>>(sid, cid, code8,
                                                      bucket_cnt, sums1);
    k_tab<<<42, 256, 0, stream>>>(sW, cW, W1l, W1r, b1, W2l, W2r,
                                  TsL, tblR, wpk2);

    // ---- bucket CSR build; k_place fuses layer-1 h1 computation ----
    k_bucket<<<NBLK_E, 256, 0, stream>>>(esrc, edst, code8, bucket_cnt, staged);
    k_bscan<<<1, 512, 0, stream>>>(bucket_cnt, bucket_off, row_ptr);
    k_place<<<NB, 256, 0, stream>>>(staged, bucket_off, code8, TsL, tblR,
                                    row_ptr, csr_src, h1b, sums1, sumsq1);

    // ---- act1 materialization (BN1 inlined, + zero graph_x) ----
    k_act<<<(N_NODES * 16 + 255) / 256, 256, 0, stream>>>(h1b, sums1, sumsq1,
                                                          g1, be1, act1b, graph_x);

    // ---- layer 2 (XCD-aligned gather -> batched MFMA) ----
    k_gather2<<<8 * 784, 512, 0, stream>>>(act1b, row_ptr, csr_src, meanb);
    k_gemm2<<<NBLK_G2, 256, 0, stream>>>(meanb, act1b, wpk2, b2,
                                         h2b, sums2, sumsq2);

    // ---- pool (BN2 inlined + relu) + classifier ----
    k_pool<<<1024, 256, 0, stream>>>(h2b, batch, sums2, sumsq2, g2, be2, graph_x);
    k_cls<<<(NGRAPH * NCLS + 255) / 256, 256, 0, stream>>>(graph_x, Wlin, blin, out);
}